// Round 1
// baseline (83.477 us; speedup 1.0000x reference)
//
#include <hip/hip_runtime.h>

#define N 512
#define P 2
#define DX 128
#define K 127               // columns of d_prev / xr
#define CLAMP_C 1e-4f
#define LOG2PI_C 1.8378770664093453f

// ws layout (float offsets)
#define WS_DT    0          // K*N = 65024 floats, dT[k*N + i] = d[i,k]
#define WS_XRT   65024      // K*N floats, xrT[k*N + i] = x[i,k+1]
#define WS_S0    130048     // 1 float
#define WS_PART  131072     // NCHUNK * N * P floats

#define JT 4                // j-values per block
#define OUTS (JT * P)       // 8 accumulators
#define ICH 32              // i-rows per chunk
#define NCHUNK (N / ICH)    // 16
#define NIDX (K * ICH)      // 4064 (i,k) pairs per block

__global__ __launch_bounds__(512)
void prep_kernel(const float* __restrict__ x, float* __restrict__ ws) {
    const int i = threadIdx.x;                 // one row per thread, 512 threads
    float* dT  = ws + WS_DT;
    float* xrT = ws + WS_XRT;
    const float* xrow = x + i * DX;
    float dacc = 0.f;
    #pragma unroll
    for (int k = 0; k < K; ++k) {
        dacc = (dacc + xrow[k]) * 0.1f;        // scan step; d[i,k]
        dT[k * N + i]  = dacc;
        xrT[k * N + i] = xrow[k + 1];
    }
    // S0 = sum_i x[i,0]  (exact: integer-valued floats)
    __shared__ float red[512];
    red[i] = xrow[0];
    __syncthreads();
    for (int s = 256; s > 0; s >>= 1) {
        if (i < s) red[i] += red[i + s];
        __syncthreads();
    }
    if (i == 0) ws[WS_S0] = red[0];
}

__global__ __launch_bounds__(256)
void main_kernel(const float* __restrict__ z, const float* __restrict__ theta,
                 float* __restrict__ ws) {
    const int jt = blockIdx.x >> 4;            // 0..127  (j tile)
    const int c  = blockIdx.x & 15;            // 0..15   (i chunk)
    const int j0 = jt * JT;
    const int i0 = c * ICH;
    const float* dT  = ws + WS_DT;
    const float* xrT = ws + WS_XRT;

    // z tile: z[(j0+jj)*4 + dz*2 + cc] -> 16 contiguous floats at z + j0*4
    float zt[OUTS * 2];
    #pragma unroll
    for (int t = 0; t < OUTS * 2; ++t) zt[t] = z[j0 * 4 + t];

    float acc[OUTS];
    #pragma unroll
    for (int o = 0; o < OUTS; ++o) acc[o] = 0.f;

    for (int idx = threadIdx.x; idx < NIDX; idx += 256) {
        const int k  = idx >> 5;               // 0..126
        const int il = idx & 31;
        const float dv  = dT[k * N + i0 + il];
        const float xv  = xrT[k * N + i0 + il];
        const float th0 = theta[k + 1];        // theta[0, k+1]
        const float th1 = theta[DX + k + 1];   // theta[1, k+1]
        #pragma unroll
        for (int o = 0; o < OUTS; ++o) {       // o = jj*2 + dz
            const float u = zt[o * 2] * th0 + zt[o * 2 + 1] * th1;
            const float s = dv + u;
            const float e = __expf(-s);
            const float p = 1.f / (1.f + e);
            const float a = (xv != 0.f) ? (p - CLAMP_C) : (1.f - p + CLAMP_C);
            acc[o] += __logf(a);
        }
    }

    // block-reduce each of the 8 accumulators (wave shuffle + LDS)
    __shared__ float red[8];
    #pragma unroll
    for (int o = 0; o < OUTS; ++o) {
        float v = acc[o];
        #pragma unroll
        for (int off = 32; off > 0; off >>= 1) v += __shfl_down(v, off, 64);
        if ((threadIdx.x & 63) == 0) red[threadIdx.x >> 6] = v;
        __syncthreads();
        if (threadIdx.x == 0) {
            const float t = red[0] + red[1] + red[2] + red[3];
            const int jj = o >> 1, dz = o & 1;
            ws[WS_PART + c * (N * P) + (j0 + jj) * P + dz] = t;
        }
        __syncthreads();
    }
}

__global__ __launch_bounds__(256)
void final_kernel(const float* __restrict__ z, const float* __restrict__ theta,
                  const float* __restrict__ ws, float* __restrict__ out) {
    const int gid = blockIdx.x * 256 + threadIdx.x;
    if (gid >= N * P) return;
    const int j = gid >> 1, dz = gid & 1;
    const float z0 = z[j * 4 + dz * 2];
    const float z1 = z[j * 4 + dz * 2 + 1];

    // lp = logpdf(z0, 1e-3) + logpdf(z1, exp(z0/4)); log(exp(z0/4)) == z0/4
    const float t1 = z0 * 1000.f;
    const float e4 = __expf(-z0 * 0.25f);
    const float t2 = z1 * e4;
    const float lp = -0.5f * t1 * t1 + 6.9077552790f   // -log(1e-3)
                   - 0.5f * t2 * t2 - z0 * 0.25f - LOG2PI_C;

    // lp0
    const float up0 = z0 * theta[0] + z1 * theta[DX];
    const float p0  = 1.f / (1.f + __expf(-up0));
    const float S0  = ws[WS_S0];
    const float lp0 = __logf(p0 - CLAMP_C) * S0
                    + __logf(1.f - p0 + CLAMP_C) * ((float)N - S0);

    float sum = 0.f;
    #pragma unroll
    for (int cc = 0; cc < NCHUNK; ++cc) sum += ws[WS_PART + cc * (N * P) + gid];
    out[gid] = lp + lp0 + sum;
}

extern "C" void kernel_launch(void* const* d_in, const int* in_sizes, int n_in,
                              void* d_out, int out_size, void* d_ws, size_t ws_size,
                              hipStream_t stream) {
    const float* z     = (const float*)d_in[0];   // (512, 2, 2)
    const float* x     = (const float*)d_in[1];   // (512, 128)
    const float* theta = (const float*)d_in[2];   // (2, 128)
    float* ws  = (float*)d_ws;
    float* out = (float*)d_out;                   // (512, 2) float32

    hipLaunchKernelGGL(prep_kernel,  dim3(1),                  dim3(512), 0, stream, x, ws);
    hipLaunchKernelGGL(main_kernel,  dim3((N / JT) * NCHUNK),  dim3(256), 0, stream, z, theta, ws);
    hipLaunchKernelGGL(final_kernel, dim3(4),                  dim3(256), 0, stream, z, theta, ws, out);
}

// Round 2
// 55.786 us; speedup vs baseline: 1.4964x; 1.4964x over previous
//
#include <hip/hip_runtime.h>

#define N 512
#define P 2
#define DX 128
#define K 127               // columns of d_prev / xr
#define CLAMP_C 1e-4f
#define LOG2PI_C 1.8378770664093453f

// ws layout (float offsets)
#define WS_EDX   0          // 512*128 floats: edx[i*128+k] = sign(x[i,k+1]) packed on exp(-d[i,k])
#define WS_S0    65536      // 1 float
#define WS_PART  65600      // NCHUNK * N * P floats

#define JT 4                // j-values per block
#define OUTS (JT * P)       // 8 accumulators
#define ICH 32              // i-rows per chunk
#define NCHUNK (N / ICH)    // 16

__global__ __launch_bounds__(512)
void prep_kernel(const float* __restrict__ x, float* __restrict__ ws) {
    const int i = threadIdx.x;                 // one row per thread, 512 threads
    const float* xrow = x + i * DX;
    float* edx = ws + WS_EDX + i * 128;
    float dacc = 0.f;
    for (int k = 0; k < K; ++k) {
        dacc = (dacc + xrow[k]) * 0.1f;        // d[i,k]
        const float ed = __expf(-dacc);        // always in (0.89, 1], never 0
        edx[k] = (xrow[k + 1] != 0.f) ? -ed : ed;   // pack x[i,k+1] into sign bit
    }
    edx[K] = 1.0f;                             // pad lane (k=127), excluded by valid mask

    // S0 = sum_i x[i,0]  (exact: integer-valued floats)
    __shared__ float red[512];
    red[i] = xrow[0];
    __syncthreads();
    for (int s = 256; s > 0; s >>= 1) {
        if (i < s) red[i] += red[i + s];
        __syncthreads();
    }
    if (i == 0) ws[WS_S0] = red[0];
}

__global__ __launch_bounds__(256)
void main_kernel(const float* __restrict__ z, const float* __restrict__ theta,
                 float* __restrict__ ws) {
    const int jt = blockIdx.x >> 4;            // 0..127  (j tile)
    const int c  = blockIdx.x & 15;            // 0..15   (i chunk)
    const int j0 = jt * JT;
    const int i0 = c * ICH;
    const int tid  = threadIdx.x;
    const int k    = tid & 127;                // this thread's k (k-major mapping)
    const int half = tid >> 7;                 // which 16-row half of the chunk
    const int ke   = (k < K) ? k : (K - 1);
    const bool valid = (k < K);

    const float th0 = theta[ke + 1];           // theta[0, k+1]
    const float th1 = theta[DX + ke + 1];      // theta[1, k+1]

    // eu[o] = exp(-u(o,k)),  o = jj*2 + dz
    float eu[OUTS];
    #pragma unroll
    for (int o = 0; o < OUTS; ++o) {
        const float z0 = z[j0 * 4 + o * 2];
        const float z1 = z[j0 * 4 + o * 2 + 1];
        eu[o] = __expf(-(z0 * th0 + z1 * th1));
    }

    const float* EDX = ws + WS_EDX;
    float accN[OUTS], accD[OUTS];
    #pragma unroll
    for (int o = 0; o < OUTS; ++o) { accN[o] = 0.f; accD[o] = 0.f; }

    const int rbase = (i0 + half * 16) * 128 + ke;

    #pragma unroll
    for (int hb = 0; hb < 4; ++hb) {           // 4 batches of 4 rows
        float num[OUTS], den[OUTS];
        #pragma unroll
        for (int o = 0; o < OUTS; ++o) { num[o] = 1.f; den[o] = 1.f; }
        #pragma unroll
        for (int hh = 0; hh < 4; ++hh) {
            const float eds = EDX[rbase + (hb * 4 + hh) * 128];
            const float xv1 = (eds < 0.f) ? 1.f : 0.f;              // x[i,k+1]
            const float ca  = fmaf(xv1, -(1.f + 2.f * CLAMP_C), 1.f + CLAMP_C);
            const float cb  = fmaf(xv1, 1.f - 2.f * CLAMP_C, CLAMP_C);
            const float ed  = __builtin_fabsf(eds);
            #pragma unroll
            for (int o = 0; o < OUTS; ++o) {
                const float e = ed * eu[o];                          // exp(-(d+u))
                den[o] = __builtin_fmaf(den[o], e, den[o]);          // *= (1+e)
                num[o] *= __builtin_fmaf(ca, e, cb);                 // *= clamped numerator
            }
        }
        #pragma unroll
        for (int o = 0; o < OUTS; ++o) {
            accN[o] += __logf(num[o]);
            accD[o] += __logf(den[o]);
        }
    }

    // block-reduce each of the 8 accumulators (wave shuffle + LDS)
    __shared__ float red[8];
    #pragma unroll
    for (int o = 0; o < OUTS; ++o) {
        float v = valid ? (accN[o] - accD[o]) : 0.f;
        #pragma unroll
        for (int off = 32; off > 0; off >>= 1) v += __shfl_down(v, off, 64);
        if ((tid & 63) == 0) red[tid >> 6] = v;
        __syncthreads();
        if (tid == 0) {
            const float t = red[0] + red[1] + red[2] + red[3];
            const int jj = o >> 1, dz = o & 1;
            ws[WS_PART + c * (N * P) + (j0 + jj) * P + dz] = t;
        }
        __syncthreads();
    }
}

__global__ __launch_bounds__(256)
void final_kernel(const float* __restrict__ z, const float* __restrict__ theta,
                  const float* __restrict__ ws, float* __restrict__ out) {
    const int gid = blockIdx.x * 256 + threadIdx.x;
    if (gid >= N * P) return;
    const int j = gid >> 1, dz = gid & 1;
    const float z0 = z[j * 4 + dz * 2];
    const float z1 = z[j * 4 + dz * 2 + 1];

    // lp = logpdf(z0, 1e-3) + logpdf(z1, exp(z0/4)); log(exp(z0/4)) == z0/4
    const float t1 = z0 * 1000.f;
    const float e4 = __expf(-z0 * 0.25f);
    const float t2 = z1 * e4;
    const float lp = -0.5f * t1 * t1 + 6.9077552790f   // -log(1e-3)
                   - 0.5f * t2 * t2 - z0 * 0.25f - LOG2PI_C;

    // lp0
    const float up0 = z0 * theta[0] + z1 * theta[DX];
    const float p0  = 1.f / (1.f + __expf(-up0));
    const float S0  = ws[WS_S0];
    const float lp0 = __logf(p0 - CLAMP_C) * S0
                    + __logf(1.f - p0 + CLAMP_C) * ((float)N - S0);

    float sum = 0.f;
    #pragma unroll
    for (int cc = 0; cc < NCHUNK; ++cc) sum += ws[WS_PART + cc * (N * P) + gid];
    out[gid] = lp + lp0 + sum;
}

extern "C" void kernel_launch(void* const* d_in, const int* in_sizes, int n_in,
                              void* d_out, int out_size, void* d_ws, size_t ws_size,
                              hipStream_t stream) {
    const float* z     = (const float*)d_in[0];   // (512, 2, 2)
    const float* x     = (const float*)d_in[1];   // (512, 128)
    const float* theta = (const float*)d_in[2];   // (2, 128)
    float* ws  = (float*)d_ws;
    float* out = (float*)d_out;                   // (512, 2) float32

    hipLaunchKernelGGL(prep_kernel,  dim3(1),                 dim3(512), 0, stream, x, ws);
    hipLaunchKernelGGL(main_kernel,  dim3((N / JT) * NCHUNK), dim3(256), 0, stream, z, theta, ws);
    hipLaunchKernelGGL(final_kernel, dim3(4),                 dim3(256), 0, stream, z, theta, ws, out);
}

// Round 3
// 27.168 us; speedup vs baseline: 3.0727x; 2.0534x over previous
//
#include <hip/hip_runtime.h>

#define N 512
#define P 2
#define DX 128
#define K 127               // columns of d_prev / xr
#define CLAMP_C 1e-4f
#define LOG2PI_C 1.8378770664093453f

// ws layout (float offsets)
#define WS_EDX   0          // 512*128 floats: edx[i*128+k] = sign(x[i,k+1]) packed on exp(-d[i,k])
#define WS_S0    65536      // 1 float
#define WS_PART  65600      // NCHUNK * N * P floats

#define JT 4                // j-values per block
#define OUTS (JT * P)       // 8 accumulators
#define ICH 32              // i-rows per chunk
#define NCHUNK (N / ICH)    // 16

#define PB 8                // prep blocks
#define PROWS (N / PB)      // 64 rows per prep block

__global__ __launch_bounds__(256)
void prep_kernel(const float* __restrict__ x, float* __restrict__ ws) {
    __shared__ float xs[PROWS * 129];          // padded rows: bank-conflict-free scan
    const int tid = threadIdx.x;
    const int i0 = blockIdx.x * PROWS;

    // S0 (block 0 only): strided reads of x[i,0], overlapped before the barrier
    float s0part = 0.f;
    if (blockIdx.x == 0) {
        s0part = x[tid * DX] + x[(tid + 256) * DX];
    }

    // stage 1: coalesced float4 load of 64 rows x 128 cols into padded LDS
    const float4* xg = (const float4*)(x + i0 * DX);
    #pragma unroll
    for (int t = tid; t < PROWS * 32; t += 256) {   // 2048 float4 / 256 threads
        const int r = t >> 5, c4 = t & 31;
        const float4 v = xg[t];
        float* dst = xs + r * 129 + c4 * 4;
        dst[0] = v.x; dst[1] = v.y; dst[2] = v.z; dst[3] = v.w;
    }
    __syncthreads();

    // stage 2: sequential decayed scan per row, in place (read row[k+1] before
    // overwriting row[k] with sign-packed exp(-d))
    if (tid < PROWS) {
        float* row = xs + tid * 129;
        float dacc = 0.f;
        float xk = row[0];
        for (int k = 0; k < K; ++k) {
            dacc = (dacc + xk) * 0.1f;             // d[i,k]
            const float xk1 = row[k + 1];
            const float ed = __expf(-dacc);        // in (0.89, 1]
            row[k] = (xk1 != 0.f) ? -ed : ed;      // pack x[i,k+1] into sign
            xk = xk1;
        }
        row[K] = 1.0f;                             // pad lane (masked in main)
    }
    __syncthreads();

    // stage 3: coalesced store LDS -> global
    float* edx = ws + WS_EDX + i0 * 128;
    #pragma unroll
    for (int t = tid; t < PROWS * 128; t += 256) {
        const int r = t >> 7, c = t & 127;
        edx[t] = xs[r * 129 + c];
    }

    if (blockIdx.x == 0) {
        __shared__ float red[256];
        red[tid] = s0part;
        __syncthreads();
        for (int s = 128; s > 0; s >>= 1) {
            if (tid < s) red[tid] += red[tid + s];
            __syncthreads();
        }
        if (tid == 0) ws[WS_S0] = red[0];
    }
}

__global__ __launch_bounds__(256)
void main_kernel(const float* __restrict__ z, const float* __restrict__ theta,
                 float* __restrict__ ws) {
    const int jt = blockIdx.x >> 4;            // 0..127  (j tile)
    const int c  = blockIdx.x & 15;            // 0..15   (i chunk)
    const int j0 = jt * JT;
    const int i0 = c * ICH;
    const int tid  = threadIdx.x;
    const int k    = tid & 127;                // this thread's k (k-major mapping)
    const int half = tid >> 7;                 // which 16-row half of the chunk
    const int ke   = (k < K) ? k : (K - 1);
    const bool valid = (k < K);

    const float th0 = theta[ke + 1];           // theta[0, k+1]
    const float th1 = theta[DX + ke + 1];      // theta[1, k+1]

    // eu[o] = exp(-u(o,k)),  o = jj*2 + dz
    float eu[OUTS];
    #pragma unroll
    for (int o = 0; o < OUTS; ++o) {
        const float z0 = z[j0 * 4 + o * 2];
        const float z1 = z[j0 * 4 + o * 2 + 1];
        eu[o] = __expf(-(z0 * th0 + z1 * th1));
    }

    const float* EDX = ws + WS_EDX;
    float acc[OUTS];
    #pragma unroll
    for (int o = 0; o < OUTS; ++o) acc[o] = 0.f;

    const int rbase = (i0 + half * 16) * 128 + ke;

    // 2 batches of 8 rows; products stay in f32 range:
    // den <= (1+e)^8 <= ~7e20, num >= (1e-4)^8 = 1e-32
    #pragma unroll
    for (int hb = 0; hb < 2; ++hb) {
        float num[OUTS], den[OUTS];
        #pragma unroll
        for (int o = 0; o < OUTS; ++o) { num[o] = 1.f; den[o] = 1.f; }
        #pragma unroll
        for (int hh = 0; hh < 8; ++hh) {
            const float eds = EDX[rbase + (hb * 8 + hh) * 128];
            const float xv1 = (eds < 0.f) ? 1.f : 0.f;              // x[i,k+1]
            const float ca  = fmaf(xv1, -(1.f + 2.f * CLAMP_C), 1.f + CLAMP_C);
            const float cb  = fmaf(xv1, 1.f - 2.f * CLAMP_C, CLAMP_C);
            const float ed  = __builtin_fabsf(eds);
            #pragma unroll
            for (int o = 0; o < OUTS; ++o) {
                const float e = ed * eu[o];                          // exp(-(d+u))
                den[o] = __builtin_fmaf(den[o], e, den[o]);          // *= (1+e)
                num[o] *= __builtin_fmaf(ca, e, cb);                 // *= clamped numerator
            }
        }
        #pragma unroll
        for (int o = 0; o < OUTS; ++o) {
            acc[o] += __logf(num[o]) - __logf(den[o]);
        }
    }

    // single-barrier block reduction of all 8 accumulators
    __shared__ float red[4][OUTS];
    #pragma unroll
    for (int o = 0; o < OUTS; ++o) {
        float v = valid ? acc[o] : 0.f;
        #pragma unroll
        for (int off = 32; off > 0; off >>= 1) v += __shfl_down(v, off, 64);
        if ((tid & 63) == 0) red[tid >> 6][o] = v;
    }
    __syncthreads();
    if (tid < OUTS) {
        const float t = red[0][tid] + red[1][tid] + red[2][tid] + red[3][tid];
        const int jj = tid >> 1, dz = tid & 1;
        ws[WS_PART + c * (N * P) + (j0 + jj) * P + dz] = t;
    }
}

__global__ __launch_bounds__(256)
void final_kernel(const float* __restrict__ z, const float* __restrict__ theta,
                  const float* __restrict__ ws, float* __restrict__ out) {
    const int gid = blockIdx.x * 256 + threadIdx.x;
    if (gid >= N * P) return;
    const int j = gid >> 1, dz = gid & 1;
    const float z0 = z[j * 4 + dz * 2];
    const float z1 = z[j * 4 + dz * 2 + 1];

    // lp = logpdf(z0, 1e-3) + logpdf(z1, exp(z0/4)); log(exp(z0/4)) == z0/4
    const float t1 = z0 * 1000.f;
    const float e4 = __expf(-z0 * 0.25f);
    const float t2 = z1 * e4;
    const float lp = -0.5f * t1 * t1 + 6.9077552790f   // -log(1e-3)
                   - 0.5f * t2 * t2 - z0 * 0.25f - LOG2PI_C;

    // lp0
    const float up0 = z0 * theta[0] + z1 * theta[DX];
    const float p0  = 1.f / (1.f + __expf(-up0));
    const float S0  = ws[WS_S0];
    const float lp0 = __logf(p0 - CLAMP_C) * S0
                    + __logf(1.f - p0 + CLAMP_C) * ((float)N - S0);

    float sum = 0.f;
    #pragma unroll
    for (int cc = 0; cc < NCHUNK; ++cc) sum += ws[WS_PART + cc * (N * P) + gid];
    out[gid] = lp + lp0 + sum;
}

extern "C" void kernel_launch(void* const* d_in, const int* in_sizes, int n_in,
                              void* d_out, int out_size, void* d_ws, size_t ws_size,
                              hipStream_t stream) {
    const float* z     = (const float*)d_in[0];   // (512, 2, 2)
    const float* x     = (const float*)d_in[1];   // (512, 128)
    const float* theta = (const float*)d_in[2];   // (2, 128)
    float* ws  = (float*)d_ws;
    float* out = (float*)d_out;                   // (512, 2) float32

    hipLaunchKernelGGL(prep_kernel,  dim3(PB),                dim3(256), 0, stream, x, ws);
    hipLaunchKernelGGL(main_kernel,  dim3((N / JT) * NCHUNK), dim3(256), 0, stream, z, theta, ws);
    hipLaunchKernelGGL(final_kernel, dim3(4),                 dim3(256), 0, stream, z, theta, ws, out);
}